// Round 1
// baseline (1374.997 us; speedup 1.0000x reference)
//
#include <hip/hip_runtime.h>
#include <hip/hip_bf16.h>
#include <cstdint>

#define N_NODES 100000

// ---------------- degree / norm ----------------

__global__ void k_degree(const int* __restrict__ dst, float* __restrict__ deg, int E) {
    int e = blockIdx.x * blockDim.x + threadIdx.x;
    if (e < E) atomicAdd(&deg[dst[e]], 1.0f);
}

__global__ void k_dinv(float* __restrict__ d, int n) {
    int i = blockIdx.x * blockDim.x + threadIdx.x;
    if (i < n) d[i] = rsqrtf(d[i] + 1.0f);
}

__global__ void k_enorm(const int* __restrict__ src, const int* __restrict__ dst,
                        const float* __restrict__ dinv, float* __restrict__ enorm, int E) {
    int e = blockIdx.x * blockDim.x + threadIdx.x;
    if (e < E) enorm[e] = dinv[src[e]] * dinv[dst[e]];
}

// ---------------- layer 1 GEMM: x(N,512) @ W1(512,8) ----------------
// thread-per-row; k-loop is wave-uniform so sW reads are conflict-free broadcasts.
// Fuses self-term: agg = xw * dinv^2 (so scatter can atomically add on top).

__global__ void k_gemm1(const float* __restrict__ x, const float* __restrict__ W,
                        const float* __restrict__ dinv, float* __restrict__ xw,
                        float* __restrict__ agg, int n) {
    __shared__ float sW[512 * 8];
    for (int i = threadIdx.x; i < 512 * 8; i += blockDim.x) sW[i] = W[i];
    __syncthreads();
    int r = blockIdx.x * blockDim.x + threadIdx.x;
    if (r >= n) return;
    const float4* xr = (const float4*)(x + (size_t)r * 512);
    float acc[8];
#pragma unroll
    for (int c = 0; c < 8; ++c) acc[c] = 0.f;
    for (int t = 0; t < 128; ++t) {
        float4 v = xr[t];
        const float* sw = &sW[t * 32];
#pragma unroll
        for (int c = 0; c < 8; ++c)
            acc[c] += v.x * sw[c] + v.y * sw[8 + c] + v.z * sw[16 + c] + v.w * sw[24 + c];
    }
    float di = dinv[r], di2 = di * di;
    float4 a0 = make_float4(acc[0], acc[1], acc[2], acc[3]);
    float4 a1 = make_float4(acc[4], acc[5], acc[6], acc[7]);
    float4* xwo = (float4*)(xw + (size_t)r * 8);
    xwo[0] = a0; xwo[1] = a1;
    float4* ago = (float4*)(agg + (size_t)r * 8);
    ago[0] = make_float4(acc[0] * di2, acc[1] * di2, acc[2] * di2, acc[3] * di2);
    ago[1] = make_float4(acc[4] * di2, acc[5] * di2, acc[6] * di2, acc[7] * di2);
}

// ---------------- small GEMMs: h(N,FIN) @ W(FIN,FOUT) ----------------

template <int FIN, int FOUT>
__global__ void k_gemm_small(const float* __restrict__ h, const float* __restrict__ W,
                             const float* __restrict__ dinv, float* __restrict__ xw,
                             float* __restrict__ agg, int n) {
    __shared__ float sW[FIN * FOUT];
    for (int i = threadIdx.x; i < FIN * FOUT; i += blockDim.x) sW[i] = W[i];
    __syncthreads();
    int r = blockIdx.x * blockDim.x + threadIdx.x;
    if (r >= n) return;
    float in[FIN];
    const float4* hp = (const float4*)(h + (size_t)r * FIN);
#pragma unroll
    for (int t = 0; t < FIN / 4; ++t) {
        float4 v = hp[t];
        in[t * 4 + 0] = v.x; in[t * 4 + 1] = v.y; in[t * 4 + 2] = v.z; in[t * 4 + 3] = v.w;
    }
    float di = dinv[r], di2 = di * di;
    float4* xwo = (float4*)(xw + (size_t)r * FOUT);
    float4* ago = (float4*)(agg + (size_t)r * FOUT);
#pragma unroll
    for (int c = 0; c < FOUT; c += 4) {
        float s[4];
#pragma unroll
        for (int j = 0; j < 4; ++j) {
            float a = 0.f;
#pragma unroll
            for (int k = 0; k < FIN; ++k) a += in[k] * sW[k * FOUT + c + j];
            s[j] = a;
        }
        xwo[c / 4] = make_float4(s[0], s[1], s[2], s[3]);
        ago[c / 4] = make_float4(s[0] * di2, s[1] * di2, s[2] * di2, s[3] * di2);
    }
}

// ---------------- edge scatter: one thread per (edge, feature) ----------------

template <int F>
__global__ void k_scatter(const int* __restrict__ src, const int* __restrict__ dst,
                          const float* __restrict__ enorm, const float* __restrict__ xw,
                          float* __restrict__ agg, int E) {
    int id = blockIdx.x * blockDim.x + threadIdx.x;
    int e = id / F;
    int c = id % F;
    if (e < E) {
        int s = src[e];
        float v = xw[(size_t)s * F + c] * enorm[e];
        atomicAdd(&agg[(size_t)dst[e] * F + c], v);
    }
}

// ---------------- finalize: h = (relu?)(agg + b), in place ----------------

template <int F, bool RELU>
__global__ void k_finalize(float* __restrict__ agg, const float* __restrict__ b, int n) {
    int i = blockIdx.x * blockDim.x + threadIdx.x;
    if (i < n) {
        float v = agg[i] + b[i % F];
        if (RELU) v = fmaxf(v, 0.f);
        agg[i] = v;
    }
}

// ---------------- sample head: one wave per sample ----------------

__global__ void k_samples(const int* __restrict__ samples, const float* __restrict__ h3,
                          const float* __restrict__ Wfc, const float* __restrict__ bfc,
                          float* __restrict__ out, int S) {
    int gid = blockIdx.x * blockDim.x + threadIdx.x;
    int wid = gid >> 6;
    int lane = threadIdx.x & 63;
    if (wid >= S) return;
    int node = samples[wid * 2 + (lane >> 5)];           // lane<32 -> x_i, else x_j
    float v = h3[(size_t)node * 32 + (lane & 31)] * Wfc[lane];
#pragma unroll
    for (int off = 32; off > 0; off >>= 1) v += __shfl_down(v, off);
    if (lane == 0) out[wid] = 1.0f / (1.0f + __expf(-(v + bfc[0])));
}

// ---------------- launch ----------------

extern "C" void kernel_launch(void* const* d_in, const int* in_sizes, int n_in,
                              void* d_out, int out_size, void* d_ws, size_t ws_size,
                              hipStream_t stream) {
    const float* x   = (const float*)d_in[0];
    const int*   ei  = (const int*)d_in[1];
    const int*   smp = (const int*)d_in[2];
    const float* W1  = (const float*)d_in[3];
    const float* b1  = (const float*)d_in[4];
    const float* W2  = (const float*)d_in[5];
    const float* b2  = (const float*)d_in[6];
    const float* W3  = (const float*)d_in[7];
    const float* b3  = (const float*)d_in[8];
    const float* Wfc = (const float*)d_in[9];
    const float* bfc = (const float*)d_in[10];
    float* out = (float*)d_out;

    const int E = in_sizes[1] / 2;
    const int S = in_sizes[2] / 2;
    const int N = N_NODES;
    const int* src = ei;         // edge_index row 0
    const int* dst = ei + E;     // edge_index row 1

    float* w = (float*)d_ws;
    size_t off = 0;
    auto alloc = [&](size_t nf) {
        float* p = w + off;
        off += (nf + 255) & ~(size_t)255;
        return p;
    };
    float* dinv = alloc(N);
    float* enorm = alloc(E);
    float* xw1 = alloc((size_t)N * 8);
    float* agg1 = alloc((size_t)N * 8);
    float* xw2 = alloc((size_t)N * 16);
    float* agg2 = alloc((size_t)N * 16);
    float* xw3 = alloc((size_t)N * 32);
    float* agg3 = alloc((size_t)N * 32);

    dim3 B(256);

    hipMemsetAsync(dinv, 0, N * sizeof(float), stream);
    k_degree<<<dim3((E + 255) / 256), B, 0, stream>>>(dst, dinv, E);
    k_dinv<<<dim3((N + 255) / 256), B, 0, stream>>>(dinv, N);
    k_enorm<<<dim3((E + 255) / 256), B, 0, stream>>>(src, dst, dinv, enorm, E);

    // layer 1: 512 -> 8, relu
    k_gemm1<<<dim3((N + 255) / 256), B, 0, stream>>>(x, W1, dinv, xw1, agg1, N);
    k_scatter<8><<<dim3((E * 8 + 255) / 256), B, 0, stream>>>(src, dst, enorm, xw1, agg1, E);
    k_finalize<8, true><<<dim3((N * 8 + 255) / 256), B, 0, stream>>>(agg1, b1, N * 8);

    // layer 2: 8 -> 16, relu
    k_gemm_small<8, 16><<<dim3((N + 255) / 256), B, 0, stream>>>(agg1, W2, dinv, xw2, agg2, N);
    k_scatter<16><<<dim3((E * 16 + 255) / 256), B, 0, stream>>>(src, dst, enorm, xw2, agg2, E);
    k_finalize<16, true><<<dim3((N * 16 + 255) / 256), B, 0, stream>>>(agg2, b2, N * 16);

    // layer 3: 16 -> 32, no relu
    k_gemm_small<16, 32><<<dim3((N + 255) / 256), B, 0, stream>>>(agg2, W3, dinv, xw3, agg3, N);
    k_scatter<32><<<dim3((E * 32 + 255) / 256), B, 0, stream>>>(src, dst, enorm, xw3, agg3, E);
    k_finalize<32, false><<<dim3((N * 32 + 255) / 256), B, 0, stream>>>(agg3, b3, N * 32);

    // head: 1M samples, one wave each
    k_samples<<<dim3(((size_t)S * 64 + 255) / 256), B, 0, stream>>>(smp, agg3, Wfc, bfc, out, S);
}

// Round 2
// 1250.018 us; speedup vs baseline: 1.1000x; 1.1000x over previous
//
#include <hip/hip_runtime.h>
#include <hip/hip_bf16.h>
#include <cstdint>

#define N_NODES 100000

// ---------------- CSR build ----------------

__global__ void k_degree(const int* __restrict__ dst, int* __restrict__ cnt, int E) {
    int e = blockIdx.x * blockDim.x + threadIdx.x;
    if (e < E) atomicAdd(&cnt[dst[e]], 1);
}

__global__ void k_dinv(const int* __restrict__ cnt, float* __restrict__ dinv, int n) {
    int i = blockIdx.x * blockDim.x + threadIdx.x;
    if (i < n) dinv[i] = rsqrtf((float)cnt[i] + 1.0f);
}

// single-block exclusive scan over cnt[0..n) -> row_start[0..n]
__global__ void k_scan(const int* __restrict__ cnt, int* __restrict__ row_start, int n) {
    __shared__ int s[1024];
    int t = threadIdx.x;
    int chunk = (n + 1023) / 1024;
    int lo = t * chunk, hi = min(lo + chunk, n);
    int sum = 0;
    for (int i = lo; i < hi; ++i) sum += cnt[i];
    s[t] = sum;
    __syncthreads();
    for (int off = 1; off < 1024; off <<= 1) {
        int v = (t >= off) ? s[t - off] : 0;
        __syncthreads();
        s[t] += v;
        __syncthreads();
    }
    int base = (t == 0) ? 0 : s[t - 1];
    for (int i = lo; i < hi; ++i) { row_start[i] = base; base += cnt[i]; }
    if (t == 1023) row_start[n] = base;
}

// bin edges by dst: csr[p] = (src, norm)
__global__ void k_bin(const int* __restrict__ src, const int* __restrict__ dst,
                      const float* __restrict__ dinv, const int* __restrict__ row_start,
                      int* __restrict__ cursor, int2* __restrict__ csr, int E) {
    int e = blockIdx.x * blockDim.x + threadIdx.x;
    if (e < E) {
        int d = dst[e];
        int s = src[e];
        int p = row_start[d] + atomicAdd(&cursor[d], 1);
        csr[p] = make_int2(s, __float_as_int(dinv[s] * dinv[d]));
    }
}

// ---------------- layer 1 GEMM: x(N,512) @ W1(512,8) ----------------

__global__ void k_gemm1(const float* __restrict__ x, const float* __restrict__ W,
                        float* __restrict__ xw, int n) {
    __shared__ float sW[512 * 8];
    for (int i = threadIdx.x; i < 512 * 8; i += blockDim.x) sW[i] = W[i];
    __syncthreads();
    int r = blockIdx.x * blockDim.x + threadIdx.x;
    if (r >= n) return;
    const float4* xr = (const float4*)(x + (size_t)r * 512);
    float acc[8];
#pragma unroll
    for (int c = 0; c < 8; ++c) acc[c] = 0.f;
    for (int t = 0; t < 128; ++t) {
        float4 v = xr[t];
        const float* sw = &sW[t * 32];
#pragma unroll
        for (int c = 0; c < 8; ++c)
            acc[c] += v.x * sw[c] + v.y * sw[8 + c] + v.z * sw[16 + c] + v.w * sw[24 + c];
    }
    float4* xwo = (float4*)(xw + (size_t)r * 8);
    xwo[0] = make_float4(acc[0], acc[1], acc[2], acc[3]);
    xwo[1] = make_float4(acc[4], acc[5], acc[6], acc[7]);
}

// ---------------- small GEMMs: h(N,FIN) @ W(FIN,FOUT) ----------------

template <int FIN, int FOUT>
__global__ void k_gemm_small(const float* __restrict__ h, const float* __restrict__ W,
                             float* __restrict__ xw, int n) {
    __shared__ float sW[FIN * FOUT];
    for (int i = threadIdx.x; i < FIN * FOUT; i += blockDim.x) sW[i] = W[i];
    __syncthreads();
    int r = blockIdx.x * blockDim.x + threadIdx.x;
    if (r >= n) return;
    float in[FIN];
    const float4* hp = (const float4*)(h + (size_t)r * FIN);
#pragma unroll
    for (int t = 0; t < FIN / 4; ++t) {
        float4 v = hp[t];
        in[t * 4 + 0] = v.x; in[t * 4 + 1] = v.y; in[t * 4 + 2] = v.z; in[t * 4 + 3] = v.w;
    }
    float4* xwo = (float4*)(xw + (size_t)r * FOUT);
#pragma unroll
    for (int c = 0; c < FOUT; c += 4) {
        float s[4];
#pragma unroll
        for (int j = 0; j < 4; ++j) {
            float a = 0.f;
#pragma unroll
            for (int k = 0; k < FIN; ++k) a += in[k] * sW[k * FOUT + c + j];
            s[j] = a;
        }
        xwo[c / 4] = make_float4(s[0], s[1], s[2], s[3]);
    }
}

// ---------------- gather-aggregate (fused self-term + bias + relu) ----------------
// thread = (node, feature c). F consecutive lanes share a node -> csr loads are
// wave-broadcast, xw[src] row loads are F*4B coalesced.

template <int F, bool RELU>
__global__ void k_gather(const float* __restrict__ xw, const int2* __restrict__ csr,
                         const int* __restrict__ row_start, const float* __restrict__ dinv,
                         const float* __restrict__ b, float* __restrict__ out, int n) {
    int gid = blockIdx.x * blockDim.x + threadIdx.x;
    int node = gid / F;
    int c = gid % F;
    if (node >= n) return;
    float di = dinv[node];
    float acc = xw[(size_t)node * F + c] * di * di;
    int k0 = row_start[node], k1 = row_start[node + 1];
    for (int k = k0; k < k1; ++k) {
        int2 p = csr[k];
        acc += xw[(size_t)p.x * F + c] * __int_as_float(p.y);
    }
    float v = acc + b[c];
    if (RELU) v = fmaxf(v, 0.f);
    out[(size_t)node * F + c] = v;
}

// ---------------- sample head: one wave per sample ----------------

__global__ void k_samples(const int* __restrict__ samples, const float* __restrict__ h3,
                          const float* __restrict__ Wfc, const float* __restrict__ bfc,
                          float* __restrict__ out, int S) {
    int gid = blockIdx.x * blockDim.x + threadIdx.x;
    int wid = gid >> 6;
    int lane = threadIdx.x & 63;
    if (wid >= S) return;
    int node = samples[wid * 2 + (lane >> 5)];           // lane<32 -> x_i, else x_j
    float v = h3[(size_t)node * 32 + (lane & 31)] * Wfc[lane];
#pragma unroll
    for (int off = 32; off > 0; off >>= 1) v += __shfl_down(v, off);
    if (lane == 0) out[wid] = 1.0f / (1.0f + __expf(-(v + bfc[0])));
}

// ---------------- launch ----------------

extern "C" void kernel_launch(void* const* d_in, const int* in_sizes, int n_in,
                              void* d_out, int out_size, void* d_ws, size_t ws_size,
                              hipStream_t stream) {
    const float* x   = (const float*)d_in[0];
    const int*   ei  = (const int*)d_in[1];
    const int*   smp = (const int*)d_in[2];
    const float* W1  = (const float*)d_in[3];
    const float* b1  = (const float*)d_in[4];
    const float* W2  = (const float*)d_in[5];
    const float* b2  = (const float*)d_in[6];
    const float* W3  = (const float*)d_in[7];
    const float* b3  = (const float*)d_in[8];
    const float* Wfc = (const float*)d_in[9];
    const float* bfc = (const float*)d_in[10];
    float* out = (float*)d_out;

    const int E = in_sizes[1] / 2;
    const int S = in_sizes[2] / 2;
    const int N = N_NODES;
    const int* src = ei;
    const int* dst = ei + E;

    char* w = (char*)d_ws;
    size_t off = 0;
    auto alloc = [&](size_t bytes) {
        char* p = w + off;
        off += (bytes + 255) & ~(size_t)255;
        return p;
    };
    int*   cnt       = (int*)alloc(N * 4);
    int*   cursor    = (int*)alloc(N * 4);
    int*   row_start = (int*)alloc((N + 1) * 4);
    float* dinv      = (float*)alloc(N * 4);
    int2*  csr       = (int2*)alloc((size_t)E * 8);
    float* xw1       = (float*)alloc((size_t)N * 8 * 4);
    float* h1        = (float*)alloc((size_t)N * 8 * 4);
    float* xw2       = (float*)alloc((size_t)N * 16 * 4);
    float* h2        = (float*)alloc((size_t)N * 16 * 4);
    float* xw3       = (float*)alloc((size_t)N * 32 * 4);
    float* h3        = (float*)alloc((size_t)N * 32 * 4);

    dim3 B(256);

    hipMemsetAsync(cnt, 0, N * 4, stream);
    hipMemsetAsync(cursor, 0, N * 4, stream);
    k_degree<<<dim3((E + 255) / 256), B, 0, stream>>>(dst, cnt, E);
    k_dinv<<<dim3((N + 255) / 256), B, 0, stream>>>(cnt, dinv, N);
    k_scan<<<dim3(1), dim3(1024), 0, stream>>>(cnt, row_start, N);
    k_bin<<<dim3((E + 255) / 256), B, 0, stream>>>(src, dst, dinv, row_start, cursor, csr, E);

    // layer 1: 512 -> 8, relu
    k_gemm1<<<dim3((N + 255) / 256), B, 0, stream>>>(x, W1, xw1, N);
    k_gather<8, true><<<dim3(((size_t)N * 8 + 255) / 256), B, 0, stream>>>(xw1, csr, row_start, dinv, b1, h1, N);

    // layer 2: 8 -> 16, relu
    k_gemm_small<8, 16><<<dim3((N + 255) / 256), B, 0, stream>>>(h1, W2, xw2, N);
    k_gather<16, true><<<dim3(((size_t)N * 16 + 255) / 256), B, 0, stream>>>(xw2, csr, row_start, dinv, b2, h2, N);

    // layer 3: 16 -> 32, no relu
    k_gemm_small<16, 32><<<dim3((N + 255) / 256), B, 0, stream>>>(h2, W3, xw3, N);
    k_gather<32, false><<<dim3(((size_t)N * 32 + 255) / 256), B, 0, stream>>>(xw3, csr, row_start, dinv, b3, h3, N);

    // head: 1M samples, one wave each
    k_samples<<<dim3(((size_t)S * 64 + 255) / 256), B, 0, stream>>>(smp, h3, Wfc, bfc, out, S);
}

// Round 3
// 989.625 us; speedup vs baseline: 1.3894x; 1.2631x over previous
//
#include <hip/hip_runtime.h>
#include <hip/hip_bf16.h>
#include <cstdint>

#define N_NODES 100000

// ---------------- CSR build ----------------

__global__ void k_degree(const int* __restrict__ dst, int* __restrict__ cnt, int E) {
    int e = blockIdx.x * blockDim.x + threadIdx.x;
    if (e < E) atomicAdd(&cnt[dst[e]], 1);
}

__global__ void k_dinv(const int* __restrict__ cnt, float* __restrict__ dinv, int n) {
    int i = blockIdx.x * blockDim.x + threadIdx.x;
    if (i < n) dinv[i] = rsqrtf((float)cnt[i] + 1.0f);
}

// single-block exclusive scan over cnt[0..n) -> row_start[0..n]
__global__ void k_scan(const int* __restrict__ cnt, int* __restrict__ row_start, int n) {
    __shared__ int s[1024];
    int t = threadIdx.x;
    int chunk = (n + 1023) / 1024;
    int lo = t * chunk, hi = min(lo + chunk, n);
    int sum = 0;
    for (int i = lo; i < hi; ++i) sum += cnt[i];
    s[t] = sum;
    __syncthreads();
    for (int off = 1; off < 1024; off <<= 1) {
        int v = (t >= off) ? s[t - off] : 0;
        __syncthreads();
        s[t] += v;
        __syncthreads();
    }
    int base = (t == 0) ? 0 : s[t - 1];
    for (int i = lo; i < hi; ++i) { row_start[i] = base; base += cnt[i]; }
    if (t == 1023) row_start[n] = base;
}

// bin edges by dst: csr[p] = (src, norm)
__global__ void k_bin(const int* __restrict__ src, const int* __restrict__ dst,
                      const float* __restrict__ dinv, const int* __restrict__ row_start,
                      int* __restrict__ cursor, int2* __restrict__ csr, int E) {
    int e = blockIdx.x * blockDim.x + threadIdx.x;
    if (e < E) {
        int d = dst[e];
        int s = src[e];
        int p = row_start[d] + atomicAdd(&cursor[d], 1);
        csr[p] = make_int2(s, __float_as_int(dinv[s] * dinv[d]));
    }
}

// ---------------- layer 1 GEMM: x(N,512) @ W1(512,8) ----------------

__global__ void k_gemm1(const float* __restrict__ x, const float* __restrict__ W,
                        float* __restrict__ xw, int n) {
    __shared__ float sW[512 * 8];
    for (int i = threadIdx.x; i < 512 * 8; i += blockDim.x) sW[i] = W[i];
    __syncthreads();
    int r = blockIdx.x * blockDim.x + threadIdx.x;
    if (r >= n) return;
    const float4* xr = (const float4*)(x + (size_t)r * 512);
    float acc[8];
#pragma unroll
    for (int c = 0; c < 8; ++c) acc[c] = 0.f;
    for (int t = 0; t < 128; ++t) {
        float4 v = xr[t];
        const float* sw = &sW[t * 32];
#pragma unroll
        for (int c = 0; c < 8; ++c)
            acc[c] += v.x * sw[c] + v.y * sw[8 + c] + v.z * sw[16 + c] + v.w * sw[24 + c];
    }
    float4* xwo = (float4*)(xw + (size_t)r * 8);
    xwo[0] = make_float4(acc[0], acc[1], acc[2], acc[3]);
    xwo[1] = make_float4(acc[4], acc[5], acc[6], acc[7]);
}

// ---------------- small GEMM with fused bias(+relu): h(N,FIN)@W(FIN,FOUT)+b ----------------

template <int FIN, int FOUT, bool RELU>
__global__ void k_gemm_small(const float* __restrict__ h, const float* __restrict__ W,
                             const float* __restrict__ b, float* __restrict__ xw, int n) {
    __shared__ float sW[FIN * FOUT];
    __shared__ float sB[FOUT];
    for (int i = threadIdx.x; i < FIN * FOUT; i += blockDim.x) sW[i] = W[i];
    for (int i = threadIdx.x; i < FOUT; i += blockDim.x) sB[i] = b[i];
    __syncthreads();
    int r = blockIdx.x * blockDim.x + threadIdx.x;
    if (r >= n) return;
    float in[FIN];
    const float4* hp = (const float4*)(h + (size_t)r * FIN);
#pragma unroll
    for (int t = 0; t < FIN / 4; ++t) {
        float4 v = hp[t];
        in[t * 4 + 0] = v.x; in[t * 4 + 1] = v.y; in[t * 4 + 2] = v.z; in[t * 4 + 3] = v.w;
    }
    float4* xwo = (float4*)(xw + (size_t)r * FOUT);
#pragma unroll
    for (int c = 0; c < FOUT; c += 4) {
        float s[4];
#pragma unroll
        for (int j = 0; j < 4; ++j) {
            float a = 0.f;
#pragma unroll
            for (int k = 0; k < FIN; ++k) a += in[k] * sW[k * FOUT + c + j];
            a += sB[c + j];
            if (RELU) a = fmaxf(a, 0.f);
            s[j] = a;
        }
        xwo[c / 4] = make_float4(s[0], s[1], s[2], s[3]);
    }
}

// ---------------- gather-aggregate (fused self-term [+ bias + relu]) ----------------
// thread = (node, feature c). F consecutive lanes share a node -> csr loads are
// wave-broadcast, xw[src] row loads are F*4B coalesced.

template <int F, bool FIN_BIAS_RELU>
__global__ void k_gather(const float* __restrict__ xw, const int2* __restrict__ csr,
                         const int* __restrict__ row_start, const float* __restrict__ dinv,
                         const float* __restrict__ b, float* __restrict__ out, int n) {
    int gid = blockIdx.x * blockDim.x + threadIdx.x;
    int node = gid / F;
    int c = gid % F;
    if (node >= n) return;
    float di = dinv[node];
    float acc = xw[(size_t)node * F + c] * di * di;
    int k0 = row_start[node], k1 = row_start[node + 1];
    for (int k = k0; k < k1; ++k) {
        int2 p = csr[k];
        acc += xw[(size_t)p.x * F + c] * __int_as_float(p.y);
    }
    if (FIN_BIAS_RELU) acc = fmaxf(acc + b[c], 0.f);
    out[(size_t)node * F + c] = acc;
}

// ---------------- head prep: fold W3/b3/Wfc into per-node 16-dot ----------------
// va[j] = sum_k W3[j][k]*Wfc[k], vb[j] = sum_k W3[j][k]*Wfc[32+k]  (j<16, k<32)
// ca = sum_k b3[k]*Wfc[k], cb = sum_k b3[k]*Wfc[32+k]

__global__ void k_prep_head(const float* __restrict__ W3, const float* __restrict__ b3,
                            const float* __restrict__ Wfc, float* __restrict__ v,
                            float* __restrict__ c) {
    int t = threadIdx.x;
    if (t < 32) {
        int j = t & 15;
        const float* wf = Wfc + (t < 16 ? 0 : 32);
        float a = 0.f;
        for (int k = 0; k < 32; ++k) a += W3[j * 32 + k] * wf[k];
        v[t] = a;
    } else if (t < 34) {
        const float* wf = Wfc + (t == 32 ? 0 : 32);
        float a = 0.f;
        for (int k = 0; k < 32; ++k) a += b3[k] * wf[k];
        c[t - 32] = a;
    }
}

// pi[n] = S3[n]·va + ca ; pj[n] = S3[n]·vb + cb
__global__ void k_node_head(const float* __restrict__ S3, const float* __restrict__ v,
                            const float* __restrict__ c, float* __restrict__ pi,
                            float* __restrict__ pj, int n) {
    int r = blockIdx.x * blockDim.x + threadIdx.x;
    if (r >= n) return;
    const float4* sp = (const float4*)(S3 + (size_t)r * 16);
    float a = 0.f, bb = 0.f;
#pragma unroll
    for (int t = 0; t < 4; ++t) {
        float4 s = sp[t];
        a += s.x * v[t * 4 + 0] + s.y * v[t * 4 + 1] + s.z * v[t * 4 + 2] + s.w * v[t * 4 + 3];
        bb += s.x * v[16 + t * 4 + 0] + s.y * v[16 + t * 4 + 1] + s.z * v[16 + t * 4 + 2] + s.w * v[16 + t * 4 + 3];
    }
    pi[r] = a + c[0];
    pj[r] = bb + c[1];
}

// ---------------- sample head: one thread per sample ----------------

__global__ void k_samples_fast(const int2* __restrict__ samples, const float* __restrict__ pi,
                               const float* __restrict__ pj, const float* __restrict__ bfc,
                               float* __restrict__ out, int S) {
    int i = blockIdx.x * blockDim.x + threadIdx.x;
    if (i >= S) return;
    int2 s = samples[i];
    float z = pi[s.x] + pj[s.y] + bfc[0];
    out[i] = 1.0f / (1.0f + __expf(-z));
}

// ---------------- launch ----------------

extern "C" void kernel_launch(void* const* d_in, const int* in_sizes, int n_in,
                              void* d_out, int out_size, void* d_ws, size_t ws_size,
                              hipStream_t stream) {
    const float* x   = (const float*)d_in[0];
    const int*   ei  = (const int*)d_in[1];
    const int*   smp = (const int*)d_in[2];
    const float* W1  = (const float*)d_in[3];
    const float* b1  = (const float*)d_in[4];
    const float* W2  = (const float*)d_in[5];
    const float* b2  = (const float*)d_in[6];
    const float* W3  = (const float*)d_in[7];
    const float* b3  = (const float*)d_in[8];
    const float* Wfc = (const float*)d_in[9];
    const float* bfc = (const float*)d_in[10];
    float* out = (float*)d_out;

    const int E = in_sizes[1] / 2;
    const int S = in_sizes[2] / 2;
    const int N = N_NODES;
    const int* src = ei;
    const int* dst = ei + E;

    char* w = (char*)d_ws;
    size_t off = 0;
    auto alloc = [&](size_t bytes) {
        char* p = w + off;
        off += (bytes + 255) & ~(size_t)255;
        return p;
    };
    int*   cnt       = (int*)alloc(N * 4);
    int*   cursor    = (int*)alloc(N * 4);
    int*   row_start = (int*)alloc((N + 1) * 4);
    float* dinv      = (float*)alloc(N * 4);
    int2*  csr       = (int2*)alloc((size_t)E * 8);
    float* xw1       = (float*)alloc((size_t)N * 8 * 4);
    float* h1        = (float*)alloc((size_t)N * 8 * 4);
    float* S2        = (float*)alloc((size_t)N * 8 * 4);
    float* h2        = (float*)alloc((size_t)N * 16 * 4);
    float* S3        = (float*)alloc((size_t)N * 16 * 4);
    float* vhead     = (float*)alloc(32 * 4);
    float* chead     = (float*)alloc(2 * 4);
    float* pi        = (float*)alloc(N * 4);
    float* pj        = (float*)alloc(N * 4);

    dim3 B(256);

    hipMemsetAsync(cnt, 0, N * 4, stream);
    hipMemsetAsync(cursor, 0, N * 4, stream);
    k_degree<<<dim3((E + 255) / 256), B, 0, stream>>>(dst, cnt, E);
    k_dinv<<<dim3((N + 255) / 256), B, 0, stream>>>(cnt, dinv, N);
    k_scan<<<dim3(1), dim3(1024), 0, stream>>>(cnt, row_start, N);
    k_bin<<<dim3((E + 255) / 256), B, 0, stream>>>(src, dst, dinv, row_start, cursor, csr, E);

    // layer 1: xw1 = x@W1 ; h1 = relu(agg8(xw1) + b1)
    k_gemm1<<<dim3((N + 255) / 256), B, 0, stream>>>(x, W1, xw1, N);
    k_gather<8, true><<<dim3(((size_t)N * 8 + 255) / 256), B, 0, stream>>>(xw1, csr, row_start, dinv, b1, h1, N);

    // layer 2 (linearity): S2 = agg8(h1) ; h2 = relu(S2@W2 + b2)
    k_gather<8, false><<<dim3(((size_t)N * 8 + 255) / 256), B, 0, stream>>>(h1, csr, row_start, dinv, nullptr, S2, N);
    k_gemm_small<8, 16, true><<<dim3((N + 255) / 256), B, 0, stream>>>(S2, W2, b2, h2, N);

    // layer 3 (linearity): S3 = agg16(h2) ; h3 = S3@W3 + b3 folded into head
    k_gather<16, false><<<dim3(((size_t)N * 16 + 255) / 256), B, 0, stream>>>(h2, csr, row_start, dinv, nullptr, S3, N);

    // head: pi/pj per node, then per-sample sigmoid
    k_prep_head<<<dim3(1), dim3(64), 0, stream>>>(W3, b3, Wfc, vhead, chead);
    k_node_head<<<dim3((N + 255) / 256), B, 0, stream>>>(S3, vhead, chead, pi, pj, N);
    k_samples_fast<<<dim3((S + 255) / 256), B, 0, stream>>>((const int2*)smp, pi, pj, bfc, out, S);
}